// Round 1
// baseline (322.117 us; speedup 1.0000x reference)
//
#include <hip/hip_runtime.h>
#include <math.h>

#define LOD 64
#define LSD 128
#define KK 16
#define BB 128
#define TT 96
#define OBSD 128
#define ENC 512
#define CH 128
#define OUTD 64

__device__ __forceinline__ float elup1f(float x) {
    return x >= 0.0f ? x + 1.0f : expf(x);
}

// ---------------- prep: band-compress basis ----------------
// basis[k][row][s], row in [0,128), s in [0,14). s<7: left block col = r-3+s; s>=7: right block.
__global__ void prep_basis(const float* __restrict__ tm11, const float* __restrict__ tm12,
                           const float* __restrict__ tm21, const float* __restrict__ tm22,
                           float* __restrict__ basis) {
    int e = blockIdx.x * blockDim.x + threadIdx.x;
    if (e >= 16 * 128 * 14) return;
    int k = e / (128 * 14);
    int rem = e % (128 * 14);
    int row = rem / 14;
    int s = rem % 14;
    int r = row & 63;
    int half = row >> 6;
    int sub = (s >= 7) ? 1 : 0;
    int ss = s - sub * 7;
    int col = r - 3 + ss;
    float v = 0.0f;
    if (col >= 0 && col < 64) {
        const float* src = half ? (sub ? tm22 : tm21) : (sub ? tm12 : tm11);
        v = src[k * 4096 + r * 64 + col];
    }
    basis[e] = v;
}

// ---------------- encoder: h=relu(obs@encW+b); wm=norm(h@Wm+bm); wc=elup1(h@Wc+bc) ----------------
#define EROWS 16
__global__ __launch_bounds__(256, 2)
void encoder_kernel(const float* __restrict__ obs,
                    const float* __restrict__ enc_W, const float* __restrict__ enc_b,
                    const float* __restrict__ wmean_W, const float* __restrict__ wmean_b,
                    const float* __restrict__ wcov_W, const float* __restrict__ wcov_b,
                    float* __restrict__ wm_out, float* __restrict__ wc_out) {
    __shared__ float obs_s[EROWS][OBSD];   // 8 KB
    __shared__ float h_s[EROWS][ENC];      // 32 KB
    __shared__ float wm_s[EROWS][LOD];     // 4 KB
    __shared__ float norm_s[EROWS];
    int tid = threadIdx.x;
    long row0 = (long)blockIdx.x * EROWS;

    for (int idx = tid; idx < EROWS * OBSD; idx += 256) {
        int r = idx >> 7, c = idx & 127;
        obs_s[r][c] = obs[(row0 + r) * OBSD + c];
    }
    __syncthreads();

    // h tile: each thread owns 2 output columns, 16 row-accumulators
    for (int p = 0; p < 2; ++p) {
        int c = tid + p * 256;
        float acc[EROWS];
        #pragma unroll
        for (int r = 0; r < EROWS; ++r) acc[r] = 0.f;
        for (int j = 0; j < OBSD; ++j) {
            float w = enc_W[j * ENC + c];
            #pragma unroll
            for (int r = 0; r < EROWS; ++r) acc[r] += obs_s[r][j] * w;
        }
        float b = enc_b[c];
        #pragma unroll
        for (int r = 0; r < EROWS; ++r) h_s[r][c] = fmaxf(acc[r] + b, 0.f);
    }
    __syncthreads();

    // wm / wc: wave0,1 -> wm rows 0..7 / 8..15 ; wave2,3 -> wc rows 0..7 / 8..15
    {
        int c = tid & 63, g = tid >> 6;
        const float* W = (g < 2) ? wmean_W : wcov_W;
        int r0 = (g & 1) * 8;
        float acc[8];
        #pragma unroll
        for (int r = 0; r < 8; ++r) acc[r] = 0.f;
        for (int j = 0; j < ENC; ++j) {
            float w = W[j * LOD + c];
            #pragma unroll
            for (int r = 0; r < 8; ++r) acc[r] += h_s[r0 + r][j] * w;
        }
        if (g < 2) {
            float b = wmean_b[c];
            #pragma unroll
            for (int r = 0; r < 8; ++r) wm_s[r0 + r][c] = acc[r] + b;
        } else {
            float b = wcov_b[c];
            #pragma unroll
            for (int r = 0; r < 8; ++r)
                wc_out[(row0 + r0 + r) * LOD + c] = elup1f(acc[r] + b);
        }
    }
    __syncthreads();
    if (tid < EROWS) {
        float ss = 0.f;
        for (int c = 0; c < 64; ++c) { float v = wm_s[tid][c]; ss += v * v; }
        norm_s[tid] = sqrtf(ss);
    }
    __syncthreads();
    for (int idx = tid; idx < EROWS * LOD; idx += 256) {
        int r = idx >> 6, c = idx & 63;
        wm_out[(row0 + r) * LOD + c] = wm_s[r][c] / norm_s[r];
    }
}

// ---------------- scan: one block per batch element, 96 sequential steps ----------------
__global__ __launch_bounds__(256, 1)
void scan_kernel(const float* __restrict__ wm_g, const float* __restrict__ wc_g,
                 const float* __restrict__ cW1, const float* __restrict__ cb1,
                 const float* __restrict__ cW2, const float* __restrict__ cb2,
                 const float* __restrict__ basis, const float* __restrict__ log_tc,
                 float* __restrict__ post_g) {
    __shared__ __align__(16) float mean_s[LSD];
    __shared__ float meanU[70], meanL[70], cuP[70], clP[70], csP[70]; // +/-3 zero pad
    __shared__ float cb1_s[128];
    __shared__ __align__(16) float cb2_s[16];
    __shared__ float tcu_s[64], tcl_s[64];
    __shared__ __align__(16) float hh_s[128];
    __shared__ float hpart_s[2][128];
    __shared__ float part_s[16 * 16];
    __shared__ __align__(16) float coeff_s[16];
    __shared__ float tm_s[128 * 15];   // row stride 15 (2-way max bank alias)
    __shared__ float nm_s[128];
    __shared__ float ncu_s[64], ncl_s[64], ncs_s[64];

    int tid = threadIdx.x;
    int b = blockIdx.x;

    // --- persistent register state ---
    float br[16][7];           // banded basis: entries e = tid + 256*m, all k
    #pragma unroll
    for (int k = 0; k < 16; ++k)
        #pragma unroll
        for (int m = 0; m < 7; ++m)
            br[k][m] = basis[k * 1792 + m * 256 + tid];

    int ta[7];                 // tm_s write addresses for my 7 entries
    #pragma unroll
    for (int m = 0; m < 7; ++m) {
        int e = m * 256 + tid;
        ta[m] = (e / 14) * 15 + (e % 14);
    }

    int ii = tid & 127, half = tid >> 7;
    float w1[64];              // my half-column of cW1
    #pragma unroll
    for (int jj = 0; jj < 64; ++jj)
        w1[jj] = cW1[(half * 64 + jj) * 128 + ii];

    int kq = tid & 15, part = tid >> 4;
    float w2[8];               // cW2 slice for logit partial
    #pragma unroll
    for (int jj = 0; jj < 8; ++jj)
        w2[jj] = cW2[(part * 8 + jj) * 16 + kq];

    // --- init carry ---
    if (tid < 70) {
        meanU[tid] = 0.f; meanL[tid] = 0.f; csP[tid] = 0.f;
        float c0 = (tid >= 3 && tid < 67) ? 10.0f : 0.f;
        cuP[tid] = c0; clP[tid] = c0;
    }
    if (tid < 128) { mean_s[tid] = 0.f; cb1_s[tid] = cb1[tid]; }
    if (tid < 16) cb2_s[tid] = cb2[tid];
    if (tid < 128) {
        float v = elup1f(log_tc[tid]);
        if (tid < 64) tcu_s[tid] = v; else tcl_s[tid - 64] = v;
    }
    __syncthreads();

    for (int t = 0; t < TT; ++t) {
        long rg = (long)b * TT + t;
        // prefetch this step's wm/wc (used in phase G; latency hidden by A..F)
        float wmv = 0.f, wcv = 0.f;
        if (tid < 64) {
            wmv = wm_g[rg * 64 + tid];
            wcv = wc_g[rg * 64 + tid];
        }
        // A: hh partials (mean @ cW1), split j-range across thread halves
        {
            const float* mh = mean_s + (half << 6);
            float acc = 0.f;
            #pragma unroll
            for (int jj = 0; jj < 64; jj += 4) {
                float4 m4 = *(const float4*)(mh + jj);
                acc += w1[jj] * m4.x + w1[jj + 1] * m4.y + w1[jj + 2] * m4.z + w1[jj + 3] * m4.w;
            }
            hpart_s[half][ii] = acc;
        }
        __syncthreads();
        // B: hh = relu(sum + bias)
        if (tid < 128)
            hh_s[tid] = fmaxf(hpart_s[0][tid] + hpart_s[1][tid] + cb1_s[tid], 0.f);
        __syncthreads();
        // C: logit partials (hh @ cW2), 16 j-chunks of 8
        {
            const float* hp = hh_s + part * 8;
            float4 h0 = *(const float4*)(hp);
            float4 h1 = *(const float4*)(hp + 4);
            float pl = w2[0] * h0.x + w2[1] * h0.y + w2[2] * h0.z + w2[3] * h0.w
                     + w2[4] * h1.x + w2[5] * h1.y + w2[6] * h1.z + w2[7] * h1.w;
            part_s[kq * 16 + part] = pl;
        }
        __syncthreads();
        // D: reduce + softmax over 16 (lanes 0..15 of wave 0)
        if (tid < 16) {
            float lg = cb2_s[tid];
            #pragma unroll
            for (int p = 0; p < 16; ++p) lg += part_s[tid * 16 + p];
            float mx = lg;
            #pragma unroll
            for (int d = 1; d < 16; d <<= 1) mx = fmaxf(mx, __shfl_xor(mx, d, 16));
            float e = expf(lg - mx);
            float ssum = e;
            #pragma unroll
            for (int d = 1; d < 16; d <<= 1) ssum += __shfl_xor(ssum, d, 16);
            coeff_s[tid] = e / ssum;
        }
        __syncthreads();
        // E: banded Tm entries from register-resident basis
        {
            float4 c0 = *(const float4*)(coeff_s);
            float4 c1 = *(const float4*)(coeff_s + 4);
            float4 c2 = *(const float4*)(coeff_s + 8);
            float4 c3 = *(const float4*)(coeff_s + 12);
            float ck[16] = {c0.x, c0.y, c0.z, c0.w, c1.x, c1.y, c1.z, c1.w,
                            c2.x, c2.y, c2.z, c2.w, c3.x, c3.y, c3.z, c3.w};
            #pragma unroll
            for (int m = 0; m < 7; ++m) {
                float acc = 0.f;
                #pragma unroll
                for (int k = 0; k < 16; ++k) acc += ck[k] * br[k][m];
                tm_s[ta[m]] = acc;
            }
        }
        __syncthreads();
        // F: per-wave — ncu | ncl | ncs | new_mean (all banded, slot-aligned)
        {
            int w = tid >> 6, l = tid & 63;
            if (w == 0) {
                const float* rowp = tm_s + l * 15;
                float acc = tcu_s[l];
                #pragma unroll
                for (int s = 0; s < 7; ++s) {
                    float a = rowp[s], bb = rowp[7 + s];
                    acc += a * a * cuP[l + s] + 2.f * a * bb * csP[l + s] + bb * bb * clP[l + s];
                }
                ncu_s[l] = acc;
            } else if (w == 1) {
                const float* rowp = tm_s + (64 + l) * 15;
                float acc = tcl_s[l];
                #pragma unroll
                for (int s = 0; s < 7; ++s) {
                    float a = rowp[s], bb = rowp[7 + s];
                    acc += a * a * cuP[l + s] + 2.f * a * bb * csP[l + s] + bb * bb * clP[l + s];
                }
                ncl_s[l] = acc;
            } else if (w == 2) {
                const float* ru = tm_s + l * 15;
                const float* rl = tm_s + (64 + l) * 15;
                float acc = 0.f;
                #pragma unroll
                for (int s = 0; s < 7; ++s) {
                    float ua = ru[s], ub = ru[7 + s];
                    float la = rl[s], lb = rl[7 + s];
                    acc += la * ua * cuP[l + s] + (lb * ua + la * ub) * csP[l + s] + lb * ub * clP[l + s];
                }
                ncs_s[l] = acc;
            } else {
                const float* ru = tm_s + l * 15;
                const float* rl = tm_s + (64 + l) * 15;
                float au = 0.f, al = 0.f;
                #pragma unroll
                for (int s = 0; s < 7; ++s) {
                    float mu = meanU[l + s], ml = meanL[l + s];
                    au += ru[s] * mu + ru[7 + s] * ml;
                    al += rl[s] * mu + rl[7 + s] * ml;
                }
                nm_s[l] = au; nm_s[64 + l] = al;
            }
        }
        __syncthreads();
        // G: Kalman update + carry write + post output
        if (tid < 64) {
            int i = tid;
            float ncu = ncu_s[i], ncl = ncl_s[i], ncs = ncs_s[i];
            float nmu = nm_s[i], nml = nm_s[64 + i];
            float denom = ncu + wcv;
            float qu = ncu / denom, ql = ncs / denom;
            float res = wmv - nmu;
            float pmu = nmu + qu * res;
            float pml = nml + ql * res;
            float cf = 1.f - qu;
            float pcu = cf * ncu;
            float pcl = ncl - ql * ncs;
            float pcs = cf * ncs;
            mean_s[i] = pmu; mean_s[64 + i] = pml;
            meanU[3 + i] = pmu; meanL[3 + i] = pml;
            cuP[3 + i] = pcu; clP[3 + i] = pcl; csP[3 + i] = pcs;
            post_g[rg * 128 + i] = pmu;
            post_g[rg * 128 + 64 + i] = pml;
        }
        __syncthreads();
    }
}

// ---------------- decoder: pred_mean / pred_var ----------------
#define DROWS 16
__global__ __launch_bounds__(256, 2)
void decoder_kernel(const float* __restrict__ post,
                    const float* __restrict__ dec_W, const float* __restrict__ dec_b,
                    const float* __restrict__ varh_W, const float* __restrict__ varh_b,
                    const float* __restrict__ var_W, const float* __restrict__ var_b,
                    float* __restrict__ out) {
    __shared__ float post_s[DROWS][LSD];   // 8 KB
    __shared__ float vh_s[DROWS][CH];      // 8 KB
    int tid = threadIdx.x;
    long row0 = (long)blockIdx.x * DROWS;
    for (int idx = tid; idx < DROWS * LSD; idx += 256) {
        int r = idx >> 7, c = idx & 127;
        post_s[r][c] = post[(row0 + r) * LSD + c];
    }
    __syncthreads();
    // vh = relu(post @ varh_W + b)
    {
        int c = tid & 127, rh = tid >> 7;
        int r0 = rh * 8;
        float acc[8];
        #pragma unroll
        for (int r = 0; r < 8; ++r) acc[r] = 0.f;
        for (int j = 0; j < LSD; ++j) {
            float w = varh_W[j * CH + c];
            #pragma unroll
            for (int r = 0; r < 8; ++r) acc[r] += post_s[r0 + r][j] * w;
        }
        float bb = varh_b[c];
        #pragma unroll
        for (int r = 0; r < 8; ++r) vh_s[r0 + r][c] = fmaxf(acc[r] + bb, 0.f);
    }
    // pred_mean (independent of vh_s; no sync needed yet)
    {
        int c = tid & 63, g = tid >> 6;
        int r0 = g * 4;
        float acc[4];
        #pragma unroll
        for (int r = 0; r < 4; ++r) acc[r] = 0.f;
        for (int j = 0; j < LSD; ++j) {
            float w = dec_W[j * OUTD + c];
            #pragma unroll
            for (int r = 0; r < 4; ++r) acc[r] += post_s[r0 + r][j] * w;
        }
        float bb = dec_b[c];
        #pragma unroll
        for (int r = 0; r < 4; ++r) out[(row0 + r0 + r) * 128 + c] = acc[r] + bb;
    }
    __syncthreads();
    // pred_var = elup1(vh @ var_W + b)
    {
        int c = tid & 63, g = tid >> 6;
        int r0 = g * 4;
        float acc[4];
        #pragma unroll
        for (int r = 0; r < 4; ++r) acc[r] = 0.f;
        for (int j = 0; j < CH; ++j) {
            float w = var_W[j * OUTD + c];
            #pragma unroll
            for (int r = 0; r < 4; ++r) acc[r] += vh_s[r0 + r][j] * w;
        }
        float bb = var_b[c];
        #pragma unroll
        for (int r = 0; r < 4; ++r) out[(row0 + r0 + r) * 128 + 64 + c] = elup1f(acc[r] + bb);
    }
}

extern "C" void kernel_launch(void* const* d_in, const int* in_sizes, int n_in,
                              void* d_out, int out_size, void* d_ws, size_t ws_size,
                              hipStream_t stream) {
    const float* obs     = (const float*)d_in[0];
    const float* enc_W   = (const float*)d_in[1];
    const float* enc_b   = (const float*)d_in[2];
    const float* wmean_W = (const float*)d_in[3];
    const float* wmean_b = (const float*)d_in[4];
    const float* wcov_W  = (const float*)d_in[5];
    const float* wcov_b  = (const float*)d_in[6];
    const float* cW1     = (const float*)d_in[7];
    const float* cb1     = (const float*)d_in[8];
    const float* cW2     = (const float*)d_in[9];
    const float* cb2     = (const float*)d_in[10];
    const float* tm11    = (const float*)d_in[11];
    const float* tm12    = (const float*)d_in[12];
    const float* tm21    = (const float*)d_in[13];
    const float* tm22    = (const float*)d_in[14];
    const float* log_tc  = (const float*)d_in[15];
    const float* dec_W   = (const float*)d_in[16];
    const float* dec_b   = (const float*)d_in[17];
    const float* varh_W  = (const float*)d_in[18];
    const float* varh_b  = (const float*)d_in[19];
    const float* var_W   = (const float*)d_in[20];
    const float* var_b   = (const float*)d_in[21];

    float* out = (float*)d_out;
    float* ws = (float*)d_ws;
    float* wm_ws    = ws;                 // 12288*64
    float* wc_ws    = ws + 786432;        // 12288*64
    float* post_ws  = ws + 1572864;       // 12288*128
    float* basis_ws = ws + 3145728;       // 16*128*14

    prep_basis<<<112, 256, 0, stream>>>(tm11, tm12, tm21, tm22, basis_ws);
    encoder_kernel<<<768, 256, 0, stream>>>(obs, enc_W, enc_b, wmean_W, wmean_b,
                                            wcov_W, wcov_b, wm_ws, wc_ws);
    scan_kernel<<<128, 256, 0, stream>>>(wm_ws, wc_ws, cW1, cb1, cW2, cb2,
                                         basis_ws, log_tc, post_ws);
    decoder_kernel<<<768, 256, 0, stream>>>(post_ws, dec_W, dec_b, varh_W, varh_b,
                                            var_W, var_b, out);
}